// Round 8
// baseline (489.291 us; speedup 1.0000x reference)
//
#include <hip/hip_runtime.h>
#include <cmath>

typedef unsigned short ush;  // bf16 raw bits
typedef __attribute__((ext_vector_type(8))) short short8;
typedef __attribute__((ext_vector_type(4))) float floatx4;

static constexpr int N_P = 100000, N_D = 1000, N_S = 5000, NT = N_P + N_D + N_S;
static constexpr int NC = 111000;  // concatenated dst slots: r0:1000 | r1:100000 | r2:5000 | r3:5000
static constexpr int E_TOT = 800000;

// hist-CSR geometry: r0 (drugs) 256 blocks, r2/r3 (diseases) 128 blocks each
static constexpr int NB0 = 256, NB2 = 128, NB3 = 128;
static constexpr int CH0 = (300000 + NB0 - 1) / NB0;   // 1172
static constexpr int CH2 = (100000 + NB2 - 1) / NB2;   // 782
static constexpr int HB0_OFF = 0;
static constexpr int HB2_OFF = NB0 * 1000;             // 256000
static constexpr int HB3_OFF = HB2_OFF + NB2 * 5000;   // 896000

__device__ __forceinline__ float b2f(ush b) { return __uint_as_float(((unsigned)b) << 16); }
__device__ __forceinline__ ush f2b(float f) {
    unsigned u = __float_as_uint(f);
    return (ush)((u + 0x7FFFu + ((u >> 16) & 1u)) >> 16);
}

// ---------------------------------------------------------------------------
// Input dtype detection (fp32 vs bf16) — scan for bf16 NaN/Inf bit patterns.
// ---------------------------------------------------------------------------
__global__ __launch_bounds__(256) void detect_kernel(const ush* __restrict__ xp,
                                                     int* __restrict__ flag) {
    __shared__ int s;
    if (threadIdx.x == 0) s = 0;
    __syncthreads();
    int c = 0;
    for (int i = threadIdx.x; i < 16384; i += 256) {
        ush h = xp[i];
        if ((h & 0x7F80) == 0x7F80) c = 1;
    }
    if (c) atomicOr(&s, 1);
    __syncthreads();
    if (threadIdx.x == 0) *flag = s;
}

struct ConvArgs {
    const void* src[21];
    long cum[22];
};

__global__ __launch_bounds__(256) void convert_kernel(ConvArgs a, ush* __restrict__ dst,
                                                      long total, const int* __restrict__ flag) {
    const int f = *flag;
    for (long g = (long)blockIdx.x * 256 + threadIdx.x; g < total; g += (long)gridDim.x * 256) {
        int t = 0;
        while (g >= a.cum[t + 1]) t++;
        long i = g - a.cum[t];
        float v = f ? ((const float*)a.src[t])[i] : b2f(((const ush*)a.src[t])[i]);
        dst[g] = f2b(v);
    }
}

// canonical-block element offsets (bf16 elements)
static constexpr size_t OFF_XP = 0;
static constexpr size_t OFF_XD = 6400000;
static constexpr size_t OFF_XS = 6528000;
static constexpr size_t OFF_WINP = 6848000;
static constexpr size_t OFF_BINP = 6852096;
static constexpr size_t OFF_WIND = 6852160;
static constexpr size_t OFF_BIND = 6860352;
static constexpr size_t OFF_WINS = 6860416;
static constexpr size_t OFF_BINS = 6864512;
static constexpr size_t OFF_WK = 6864576;
static constexpr size_t OFF_BK = 6889152;
static constexpr size_t OFF_WQ = 6889536;
static constexpr size_t OFF_BQ = 6914112;
static constexpr size_t OFF_WV = 6914496;
static constexpr size_t OFF_BV = 6939072;
static constexpr size_t OFF_WA = 6939456;
static constexpr size_t OFF_BA = 6964032;
static constexpr size_t OFF_AREL = 6964416;
static constexpr size_t OFF_MREL = 6972608;
static constexpr size_t OFF_PREL = 6980800;
static constexpr size_t OFF_SKIP = 6980832;
static constexpr size_t CW_TOTAL = 6980838;

// ---------------------------------------------------------------------------
// Hist-CSR: r0/r2/r3 use per-block LDS histograms -> HB[block][dst] (no global
// atomics); scanHB turns HB into per-(block,dst) bases + per-dst totals; fill
// uses LDS cursors only. r1 (patients, deg~3) keeps cheap per-edge atomics.
// ---------------------------------------------------------------------------
struct CsrB {
    const int* ei[3];  // r0, r2, r3 edge arrays
};

__device__ __forceinline__ void hist_geom(int b, const CsrB& c, int& r, const int*& ei, int& E,
                                          int& ndst, int& e0, int& e1, int& hb) {
    if (b < NB0) {
        r = 0; ei = c.ei[0]; E = 300000; ndst = 1000;
        e0 = b * CH0; hb = HB0_OFF + b * 1000;
    } else if (b < NB0 + NB2) {
        r = 1; ei = c.ei[1]; E = 100000; ndst = 5000;
        e0 = (b - NB0) * CH2; hb = HB2_OFF + (b - NB0) * 5000;
    } else {
        r = 2; ei = c.ei[2]; E = 100000; ndst = 5000;
        e0 = (b - NB0 - NB2) * CH2; hb = HB3_OFF + (b - NB0 - NB2) * 5000;
    }
    e1 = min(E, e0 + ((r == 0) ? CH0 : CH2));
}

__global__ __launch_bounds__(256) void count_hist_kernel(CsrB c, int* __restrict__ HB) {
    __shared__ int h[5000];
    int r, E, ndst, e0, e1, hb;
    const int* ei;
    hist_geom(blockIdx.x, c, r, ei, E, ndst, e0, e1, hb);
    for (int d = threadIdx.x; d < ndst; d += 256) h[d] = 0;
    __syncthreads();
    for (int e = e0 + threadIdx.x; e < e1; e += 256) atomicAdd(&h[ei[E + e]], 1);
    __syncthreads();
    for (int d = threadIdx.x; d < ndst; d += 256) HB[hb + d] = h[d];
}

// one thread per (relation-local dst): exclusive scan over blocks, total->CNT
__global__ __launch_bounds__(256) void scanHB_kernel(int* __restrict__ HB,
                                                     int* __restrict__ cnt) {
    int d = blockIdx.x * 256 + threadIdx.x;
    int ld, NB, base, roff, ndst;
    if (d < 1000) { ld = d; NB = NB0; base = HB0_OFF; roff = 0; ndst = 1000; }
    else if (d < 6000) { ld = d - 1000; NB = NB2; base = HB2_OFF; roff = 101000; ndst = 5000; }
    else if (d < 11000) { ld = d - 6000; NB = NB3; base = HB3_OFF; roff = 106000; ndst = 5000; }
    else return;
    int run = 0;
    for (int b = 0; b < NB; b++) {
        int t = HB[base + b * ndst + ld];
        HB[base + b * ndst + ld] = run;
        run += t;
    }
    cnt[roff + ld] = run;
}

__global__ __launch_bounds__(256) void fill_hist_kernel(CsrB c, const int* __restrict__ HB,
                                                        const int* __restrict__ rowptr,
                                                        int* __restrict__ col) {
    __shared__ int h[5000];
    int r, E, ndst, e0, e1, hb;
    const int* ei;
    hist_geom(blockIdx.x, c, r, ei, E, ndst, e0, e1, hb);
    const int roff = (r == 0) ? 0 : (r == 1) ? 101000 : 106000;
    for (int d = threadIdx.x; d < ndst; d += 256) h[d] = rowptr[roff + d] + HB[hb + d];
    __syncthreads();
    for (int e = e0 + threadIdx.x; e < e1; e += 256) {
        int d = ei[E + e];
        int slot = atomicAdd(&h[d], 1);
        col[slot] = ei[e];
    }
}

__global__ __launch_bounds__(256) void countA_kernel(const int* __restrict__ ei,
                                                     int* __restrict__ cnt) {
    int g = blockIdx.x * 256 + threadIdx.x;
    if (g >= 300000) return;
    atomicAdd(&cnt[1000 + ei[300000 + g]], 1);
}

__global__ __launch_bounds__(256) void scanA_kernel(const int* __restrict__ cnt,
                                                    int* __restrict__ tmp,
                                                    int* __restrict__ part) {
    __shared__ int ls[256];
    const int t = threadIdx.x;
    const int base = blockIdx.x * 1024 + t * 4;
    int v[4];
#pragma unroll
    for (int j = 0; j < 4; j++) v[j] = (base + j < NC) ? cnt[base + j] : 0;
    int tsum = v[0] + v[1] + v[2] + v[3];
    ls[t] = tsum;
    __syncthreads();
    for (int off = 1; off < 256; off <<= 1) {
        int y = (t >= off) ? ls[t - off] : 0;
        __syncthreads();
        ls[t] += y;
        __syncthreads();
    }
    int run = ls[t] - tsum;
#pragma unroll
    for (int j = 0; j < 4; j++) {
        if (base + j < NC) tmp[base + j] = run;
        run += v[j];
    }
    if (t == 255) part[blockIdx.x] = ls[255];
}

__global__ __launch_bounds__(256) void scanB_kernel(int* __restrict__ part, int nb) {
    __shared__ int ls[256];
    const int t = threadIdx.x;
    int x = (t < nb) ? part[t] : 0;
    ls[t] = x;
    __syncthreads();
    for (int off = 1; off < 256; off <<= 1) {
        int y = (t >= off) ? ls[t - off] : 0;
        __syncthreads();
        ls[t] += y;
        __syncthreads();
    }
    if (t < nb) part[t] = ls[t] - x;
    if (t == nb - 1) part[nb] = ls[t];
}

__global__ __launch_bounds__(256) void scanC_kernel(const int* __restrict__ tmp,
                                                    const int* __restrict__ part,
                                                    int* __restrict__ rowptr) {
    int i = blockIdx.x * 256 + threadIdx.x;
    if (i > NC) return;
    rowptr[i] = (i == NC) ? part[(NC + 1023) / 1024] : tmp[i] + part[i >> 10];
}

__global__ __launch_bounds__(256) void fillA_kernel(const int* __restrict__ ei,
                                                    const int* __restrict__ rowptr,
                                                    int* __restrict__ fillpos,
                                                    int* __restrict__ col) {
    int g = blockIdx.x * 256 + threadIdx.x;
    if (g >= 300000) return;
    int gi = 1000 + ei[300000 + g];
    int slot = rowptr[gi] + atomicAdd(&fillpos[gi], 1);
    col[slot] = ei[g];
}

// ---------------------------------------------------------------------------
// Fold a_rel/m_rel into effective K|V weights, bf16, fused per (l,r).
// ---------------------------------------------------------------------------
__global__ __launch_bounds__(256) void eff_kernel(const ush* __restrict__ CW,
                                                  ush* __restrict__ weff) {
    const int b = blockIdx.x;  // l*4+r
    const int l = b >> 2, r = b & 3;
    const int st_of[4] = {0, 1, 1, 0};
    const int st = st_of[r];
    ush* out = weff + (size_t)b * 8320;
    for (int idx = threadIdx.x; idx < 8320; idx += 256) {
        int n, k;
        if (idx < 8192) { k = idx >> 7; n = idx & 127; }
        else { k = -1; n = idx - 8192; }
        int kv = n >= 64;
        int j = n & 63, h = j >> 4, e = j & 15;
        const ush* W = CW + (kv ? OFF_WV : OFF_WK) + (size_t)(l * 3 + st) * 4096;
        const ush* B = CW + (kv ? OFF_BV : OFF_BK) + (size_t)(l * 3 + st) * 64;
        const ush* R = CW + (kv ? OFF_MREL : OFF_AREL) + (size_t)(l * 4 + r) * 1024;
        float acc = 0.f;
        if (k >= 0) {
#pragma unroll
            for (int d = 0; d < 16; d++)
                acc += b2f(W[k * 64 + h * 16 + d]) * b2f(R[h * 256 + d * 16 + e]);
        } else {
#pragma unroll
            for (int d = 0; d < 16; d++)
                acc += b2f(B[h * 16 + d]) * b2f(R[h * 256 + d * 16 + e]);
        }
        out[idx] = f2b(acc);
    }
}

// ---------------------------------------------------------------------------
// Shared MFMA tile body: Y[64 rows x NOUT] = X @ W + bias, rows at row0.
// ---------------------------------------------------------------------------
template <int K, int NOUT>
__device__ __forceinline__ void gemm_tile(const ush* __restrict__ X, const ush* __restrict__ W,
                                          const ush* __restrict__ Bb, ush* __restrict__ Y,
                                          int M, int row0) {
    constexpr int NF = (K / 32) * (NOUT / 16);
    __shared__ short sA[64][K + 8];
    __shared__ short sB[NF][512];
    const int tid = threadIdx.x;
    for (int cid = tid; cid < 64 * K / 8; cid += 256) {
        int r = cid / (K / 8), c0 = (cid % (K / 8)) * 8;
        int row = row0 + r;
        short8 v = {0, 0, 0, 0, 0, 0, 0, 0};
        if (row < M) v = *(const short8*)(const void*)(X + (size_t)row * K + c0);
        *(short8*)(&sA[r][c0]) = v;
    }
    for (int u = tid; u < NF * 64; u += 256) {
        int f = u >> 6, l = u & 63;
        int s = f / (NOUT / 16), c = f % (NOUT / 16);
        int kbase = 32 * s + ((l >> 4) << 3), n = 16 * c + (l & 15);
        short8 v;
#pragma unroll
        for (int j = 0; j < 8; j++) v[j] = (short)W[(size_t)(kbase + j) * NOUT + n];
        *(short8*)(&sB[f][l * 8]) = v;
    }
    __syncthreads();
    const int w = tid >> 6, l = tid & 63;
    floatx4 acc[NOUT / 16];
#pragma unroll
    for (int c = 0; c < NOUT / 16; c++) {
        float bv = b2f(Bb[16 * c + (l & 15)]);
        acc[c] = (floatx4){bv, bv, bv, bv};
    }
#pragma unroll
    for (int s = 0; s < K / 32; s++) {
        short8 a = *(const short8*)(&sA[16 * w + (l & 15)][32 * s + ((l >> 4) << 3)]);
#pragma unroll
        for (int c = 0; c < NOUT / 16; c++) {
            short8 b = *(const short8*)(&sB[s * (NOUT / 16) + c][l * 8]);
            acc[c] = __builtin_amdgcn_mfma_f32_16x16x32_bf16(a, b, acc[c], 0, 0, 0);
        }
    }
#pragma unroll
    for (int c = 0; c < NOUT / 16; c++)
#pragma unroll
        for (int r = 0; r < 4; r++) {
            int row = row0 + 16 * w + ((l >> 4) << 2) + r;
            if (row < M) Y[(size_t)row * NOUT + 16 * c + (l & 15)] = f2b(acc[c][r]);
        }
}

template <int K, int NOUT>
__global__ __launch_bounds__(256) void mfma_proj(const ush* __restrict__ X,
                                                 const ush* __restrict__ W,
                                                 const ush* __restrict__ bias,
                                                 ush* __restrict__ Y, int M) {
    gemm_tile<K, NOUT>(X, W, bias, Y, M, blockIdx.x * 64);
}

// Batched Q projection: blocks [0,1563) P | [1563,1579) D | [1579,1658) S
struct QArgs {
    const ush* X;
    ush* Q;
    const ush* W[3];
    const ush* Bb[3];
};
__global__ __launch_bounds__(256) void qproj_kernel(QArgs a) {
    const int b = blockIdx.x;
    int t, lb, M;
    size_t noff;
    if (b < 1563) { t = 0; lb = b; M = N_P; noff = 0; }
    else if (b < 1579) { t = 1; lb = b - 1563; M = N_D; noff = (size_t)N_P; }
    else { t = 2; lb = b - 1579; M = N_S; noff = (size_t)(N_P + N_D); }
    gemm_tile<64, 64>(a.X + noff * 64, a.W[t], a.Bb[t], a.Q + noff * 64, M, lb * 64);
}

// Batched KV projection: r0 P | r1 D | r2 D | r3 P -> per-relation KV tables
struct KVArgs {
    const ush* X[4];
    ush* Y[4];
    const ush* W[4];
    const ush* Bb[4];
};
__global__ __launch_bounds__(256) void kvproj_kernel(KVArgs a) {
    const int b = blockIdx.x;
    int r, lb, M;
    if (b < 1563) { r = 0; lb = b; M = N_P; }
    else if (b < 1579) { r = 1; lb = b - 1563; M = N_D; }
    else if (b < 1595) { r = 2; lb = b - 1579; M = N_D; }
    else { r = 3; lb = b - 1595; M = N_P; }
    gemm_tile<64, 128>(a.X[r], a.W[r], a.Bb[r], a.Y[r], M, lb * 64);
}

// ---------------------------------------------------------------------------
// Fused gather aggregation with degree-proportional lane parallelism.
// ---------------------------------------------------------------------------
struct AggrArgs {
    const int* rowptr;
    const int* col;
    const ush* KV[4];
    const ush* Q;
    const ush* prel;
    float* OUT;
};

template <int LANES>
__device__ __forceinline__ void seg_attn(const AggrArgs& a, int rel, int g, int h, int lane,
                                         const float* qf, float* o) {
    const int s0 = a.rowptr[g], s1 = a.rowptr[g + 1];
    const ush* KV = a.KV[rel];
    const float ps = b2f(a.prel[rel * 4 + h]) * 0.25f;
    float m = -1e30f, s = 0.f;
    float acc[16];
#pragma unroll
    for (int i = 0; i < 16; i++) acc[i] = 0.f;
    for (int j = s0 + lane; j < s1; j += LANES) {
        int src = a.col[j];
        const ush* kp = KV + (size_t)src * 128 + h * 16;
        short8 k0 = *(const short8*)(const void*)kp;
        short8 k1 = *(const short8*)(const void*)(kp + 8);
        short8 v0 = *(const short8*)(const void*)(kp + 64);
        short8 v1 = *(const short8*)(const void*)(kp + 72);
        float dot = 0.f;
#pragma unroll
        for (int i = 0; i < 8; i++) dot += qf[i] * b2f((ush)k0[i]);
#pragma unroll
        for (int i = 0; i < 8; i++) dot += qf[8 + i] * b2f((ush)k1[i]);
        float aa = dot * ps;
        float nm = fmaxf(m, aa);
        float e0 = __expf(m - nm), e1 = __expf(aa - nm);
        s = s * e0 + e1;
#pragma unroll
        for (int i = 0; i < 8; i++) acc[i] = acc[i] * e0 + e1 * b2f((ush)v0[i]);
#pragma unroll
        for (int i = 0; i < 8; i++) acc[8 + i] = acc[8 + i] * e0 + e1 * b2f((ush)v1[i]);
        m = nm;
    }
#pragma unroll
    for (int wd = LANES >> 1; wd >= 1; wd >>= 1) {
        float mo = __shfl_xor(m, wd);
        float so = __shfl_xor(s, wd);
        float nm = fmaxf(m, mo);
        float e0 = __expf(m - nm), e1 = __expf(mo - nm);
        s = s * e0 + so * e1;
#pragma unroll
        for (int i = 0; i < 16; i++) {
            float ao = __shfl_xor(acc[i], wd);
            acc[i] = acc[i] * e0 + ao * e1;
        }
        m = nm;
    }
    float inv = 1.f / (s + 1e-16f);
#pragma unroll
    for (int i = 0; i < 16; i++) o[i] += acc[i] * inv;
}

template <int LANES>
__device__ __forceinline__ void job_run(const AggrArgs& a, int wid, int nd, int rel, int roff,
                                        size_t xoff, int rel2, int roff2) {
    const int lane = wid % LANES;
    const int grp = wid / LANES;
    const int d = grp >> 2, h = grp & 3;
    if (d >= nd) return;
    const ush* qp = a.Q + xoff + (size_t)d * 64 + h * 16;
    short8 q0 = *(const short8*)(const void*)qp;
    short8 q1 = *(const short8*)(const void*)(qp + 8);
    float qf[16];
#pragma unroll
    for (int i = 0; i < 8; i++) { qf[i] = b2f((ush)q0[i]); qf[8 + i] = b2f((ush)q1[i]); }
    float o[16];
#pragma unroll
    for (int i = 0; i < 16; i++) o[i] = 0.f;
    seg_attn<LANES>(a, rel, roff + d, h, lane, qf, o);
    if (rel2 >= 0) seg_attn<LANES>(a, rel2, roff2 + d, h, lane, qf, o);
    if (lane == 0) {
        float* op = a.OUT + xoff + (size_t)d * 64 + h * 16;
#pragma unroll
        for (int i = 0; i < 4; i++)
            *(floatx4*)(op + 4 * i) =
                (floatx4){o[4 * i], o[4 * i + 1], o[4 * i + 2], o[4 * i + 3]};
    }
}

// blocks: [0,250) drugs L=16 | [250,563) diseases L=4 | [563,3688) patients L=2
__global__ __launch_bounds__(256) void aggr_kernel(AggrArgs a) {
    const int b = blockIdx.x, t = threadIdx.x;
    if (b < 250) {
        job_run<16>(a, b * 256 + t, N_D, 0, 0, (size_t)N_P * 64, -1, 0);
    } else if (b < 563) {
        job_run<4>(a, (b - 250) * 256 + t, N_S, 2, 101000, (size_t)(N_P + N_D) * 64, 3, 106000);
    } else {
        job_run<2>(a, (b - 563) * 256 + t, N_P, 1, 1000, 0, -1, 0);
    }
}

// ---------------------------------------------------------------------------
// Batched MFMA epilogue: x = s*(gelu(OUT) @ Wa + ba) + (1-s)*x.
// last==1: write final output (dtype per flag) to fout instead of X.
// ---------------------------------------------------------------------------
struct EpiArgs {
    const float* O;
    ush* X;
    const ush* W[3];
    const ush* Bb[3];
    const ush* skipv;  // 3 bf16 gates for this layer
    void* fout;
    const int* flag;
    int last;
};

__global__ __launch_bounds__(256) void epi_kernel(EpiArgs a) {
    const int b = blockIdx.x;
    int t, lb, M;
    size_t noff;
    if (b < 1563) { t = 0; lb = b; M = N_P; noff = 0; }
    else if (b < 1579) { t = 1; lb = b - 1563; M = N_D; noff = (size_t)N_P; }
    else { t = 2; lb = b - 1579; M = N_S; noff = (size_t)(N_P + N_D); }
    const float* O = a.O + noff * 64;
    ush* X = a.X + noff * 64;
    const ush* W = a.W[t];
    __shared__ short sA[64][72];
    __shared__ short sB[8][512];
    const int tid = threadIdx.x;
    const int row0 = lb * 64;
    for (int cid = tid; cid < 512; cid += 256) {
        int r = cid >> 3, c0 = (cid & 7) * 8;
        int row = row0 + r;
        short8 sv = {0, 0, 0, 0, 0, 0, 0, 0};
        if (row < M) {
#pragma unroll
            for (int j = 0; j < 8; j++) {
                float v = O[(size_t)row * 64 + c0 + j];
                sv[j] = (short)f2b(0.5f * v * (1.0f + erff(v * 0.70710678118654752f)));
            }
        }
        *(short8*)(&sA[r][c0]) = sv;
    }
    for (int u = tid; u < 512; u += 256) {
        int f = u >> 6, l = u & 63;
        int s = f >> 2, c = f & 3;
        int kbase = 32 * s + ((l >> 4) << 3), n = 16 * c + (l & 15);
        short8 v;
#pragma unroll
        for (int j = 0; j < 8; j++) v[j] = (short)W[(size_t)(kbase + j) * 64 + n];
        *(short8*)(&sB[f][l * 8]) = v;
    }
    __syncthreads();
    const int w = tid >> 6, l = tid & 63;
    const float sg = 1.f / (1.f + expf(-b2f(a.skipv[t])));
    floatx4 acc[4];
#pragma unroll
    for (int c = 0; c < 4; c++) {
        float bv = b2f(a.Bb[t][16 * c + (l & 15)]);
        acc[c] = (floatx4){bv, bv, bv, bv};
    }
#pragma unroll
    for (int s = 0; s < 2; s++) {
        short8 av = *(const short8*)(&sA[16 * w + (l & 15)][32 * s + ((l >> 4) << 3)]);
#pragma unroll
        for (int c = 0; c < 4; c++) {
            short8 bv = *(const short8*)(&sB[s * 4 + c][l * 8]);
            acc[c] = __builtin_amdgcn_mfma_f32_16x16x32_bf16(av, bv, acc[c], 0, 0, 0);
        }
    }
    const int fl = a.last ? *a.flag : 0;
#pragma unroll
    for (int c = 0; c < 4; c++)
#pragma unroll
        for (int r = 0; r < 4; r++) {
            int row = row0 + 16 * w + ((l >> 4) << 2) + r;
            if (row >= M) continue;
            size_t off = (size_t)row * 64 + 16 * c + (l & 15);
            float val = sg * acc[c][r] + (1.f - sg) * b2f(X[off]);
            if (!a.last) {
                X[off] = f2b(val);
            } else {
                size_t goff = (noff + row) * 64 + 16 * c + (l & 15);
                if (fl)
                    ((float*)a.fout)[goff] = val;
                else
                    ((ush*)a.fout)[goff] = f2b(val);
            }
        }
}

// ---------------------------------------------------------------------------
extern "C" void kernel_launch(void* const* d_in, const int* in_sizes, int n_in,
                              void* d_out, int out_size, void* d_ws, size_t ws_size,
                              hipStream_t stream) {
    // ---- Workspace layout (~124.5 MiB) ----
    char* w = (char*)d_ws;
    int* FLAG = (int*)w;    w += 64;
    ush* CW = (ush*)w;      w += ((CW_TOTAL * 2 + 63) / 64) * 64;
    ush* WEFFB = (ush*)w;   w += ((size_t)8 * 8320 * 2 + 63) / 64 * 64;
    ush* X = (ush*)w;       w += (size_t)NT * 64 * 2;
    ush* Q = (ush*)w;       w += (size_t)NT * 64 * 2;
    ush* KV0 = (ush*)w;     w += (size_t)N_P * 128 * 2;
    ush* KV1 = (ush*)w;     w += (size_t)N_D * 128 * 2;
    ush* KV2 = (ush*)w;     w += (size_t)N_D * 128 * 2;
    ush* KV3 = (ush*)w;     w += (size_t)N_P * 128 * 2;
    float* OUT = (float*)w; w += (size_t)NT * 64 * 4;
    int* CNT = (int*)w;     w += (size_t)NC * 4;  // r1 region doubles as fillpos
    int* TMP = (int*)w;     w += (size_t)NC * 4;
    int* PART = (int*)w;    w += 512;
    int* ROWPTR = (int*)w;  w += (size_t)(NC + 1) * 4;
    int* COL = (int*)w;     w += (size_t)E_TOT * 4;
    int* HB = (int*)OUT;    // 1.536M ints (6 MB) overlaid on OUT; dead before aggr

    // dtype detect + canonicalize
    detect_kernel<<<1, 256, 0, stream>>>((const ush*)d_in[0], FLAG);
    static const long sz[21] = {6400000, 128000, 320000, 4096, 64, 8192, 64, 4096, 64,
                                24576, 384, 24576, 384, 24576, 384, 24576, 384,
                                8192, 8192, 32, 6};
    ConvArgs ca;
    long cum = 0;
    for (int t = 0; t < 21; t++) {
        ca.src[t] = d_in[t];
        ca.cum[t] = cum;
        cum += sz[t];
    }
    ca.cum[21] = cum;
    convert_kernel<<<4096, 256, 0, stream>>>(ca, CW, cum, FLAG);

    // CSR build: hist path for r0/r2/r3 (no global atomics), per-edge for r1
    CsrB cb;
    cb.ei[0] = (const int*)d_in[21];  // r0: dst drugs
    cb.ei[1] = (const int*)d_in[23];  // r2: dst diseases
    cb.ei[2] = (const int*)d_in[24];  // r3: dst diseases
    hipMemsetAsync(CNT + 1000, 0, (size_t)100000 * 4, stream);  // r1 count region
    countA_kernel<<<(300000 + 255) / 256, 256, 0, stream>>>((const int*)d_in[22], CNT);
    count_hist_kernel<<<NB0 + NB2 + NB3, 256, 0, stream>>>(cb, HB);
    scanHB_kernel<<<(11000 + 255) / 256, 256, 0, stream>>>(HB, CNT);
    scanA_kernel<<<(NC + 1023) / 1024, 256, 0, stream>>>(CNT, TMP, PART);
    scanB_kernel<<<1, 256, 0, stream>>>(PART, (NC + 1023) / 1024);
    scanC_kernel<<<(NC + 1 + 255) / 256, 256, 0, stream>>>(TMP, PART, ROWPTR);
    hipMemsetAsync(CNT + 1000, 0, (size_t)100000 * 4, stream);  // reuse as r1 fillpos
    fillA_kernel<<<(300000 + 255) / 256, 256, 0, stream>>>((const int*)d_in[22], ROWPTR, CNT,
                                                           COL);
    fill_hist_kernel<<<NB0 + NB2 + NB3, 256, 0, stream>>>(cb, HB, ROWPTR, COL);

    eff_kernel<<<8, 256, 0, stream>>>(CW, WEFFB);

    const size_t toff[3] = {0, (size_t)N_P, (size_t)(N_P + N_D)};

    // input projections -> X
    mfma_proj<64, 64><<<(N_P + 63) / 64, 256, 0, stream>>>(
        CW + OFF_XP, CW + OFF_WINP, CW + OFF_BINP, X, N_P);
    mfma_proj<128, 64><<<(N_D + 63) / 64, 256, 0, stream>>>(
        CW + OFF_XD, CW + OFF_WIND, CW + OFF_BIND, X + toff[1] * 64, N_D);
    mfma_proj<64, 64><<<(N_S + 63) / 64, 256, 0, stream>>>(
        CW + OFF_XS, CW + OFF_WINS, CW + OFF_BINS, X + toff[2] * 64, N_S);

    for (int l = 0; l < 2; l++) {
        QArgs qa;
        qa.X = X;
        qa.Q = Q;
        for (int t = 0; t < 3; t++) {
            qa.W[t] = CW + OFF_WQ + (size_t)(l * 3 + t) * 4096;
            qa.Bb[t] = CW + OFF_BQ + (l * 3 + t) * 64;
        }
        qproj_kernel<<<1658, 256, 0, stream>>>(qa);

        KVArgs ka;
        ush* KVr[4] = {KV0, KV1, KV2, KV3};
        const int rst[4] = {0, 1, 1, 0};
        for (int r = 0; r < 4; r++) {
            ka.X[r] = X + toff[rst[r]] * 64;
            ka.Y[r] = KVr[r];
            const ush* we = WEFFB + (size_t)(l * 4 + r) * 8320;
            ka.W[r] = we;
            ka.Bb[r] = we + 8192;
        }
        kvproj_kernel<<<3158, 256, 0, stream>>>(ka);

        AggrArgs aa;
        aa.rowptr = ROWPTR;
        aa.col = COL;
        for (int r = 0; r < 4; r++) aa.KV[r] = KVr[r];
        aa.Q = Q;
        aa.prel = CW + OFF_PREL + l * 16;
        aa.OUT = OUT;
        aggr_kernel<<<3688, 256, 0, stream>>>(aa);

        EpiArgs ea;
        ea.O = OUT;
        ea.X = X;
        for (int t = 0; t < 3; t++) {
            ea.W[t] = CW + OFF_WA + (size_t)(l * 3 + t) * 4096;
            ea.Bb[t] = CW + OFF_BA + (l * 3 + t) * 64;
        }
        ea.skipv = CW + OFF_SKIP + l * 3;
        ea.fout = d_out;
        ea.flag = FLAG;
        ea.last = (l == 1) ? 1 : 0;
        epi_kernel<<<1658, 256, 0, stream>>>(ea);
    }
}

// Round 9
// 426.744 us; speedup vs baseline: 1.1466x; 1.1466x over previous
//
#include <hip/hip_runtime.h>
#include <cmath>

typedef unsigned short ush;  // bf16 raw bits
typedef __attribute__((ext_vector_type(8))) short short8;
typedef __attribute__((ext_vector_type(4))) float floatx4;

static constexpr int N_P = 100000, N_D = 1000, N_S = 5000, NT = N_P + N_D + N_S;
static constexpr int NC = 111000;  // concatenated dst slots: r0:1000 | r1:100000 | r2:5000 | r3:5000
static constexpr int E_TOT = 800000;

// hist-CSR geometry
static constexpr int NB0 = 128, NB2 = 64, NB3 = 64;
static constexpr int CH0 = (300000 + NB0 - 1) / NB0;  // 2344
static constexpr int CH2 = (100000 + NB2 - 1) / NB2;  // 1563
static constexpr int HB0_OFF = 0;                     // 128*1000
static constexpr int HB2_OFF = NB0 * 1000;            // 128000, 64*5000
static constexpr int HB3_OFF = HB2_OFF + NB2 * 5000;  // 448000, 64*5000 -> total 768000
static constexpr int NCH0 = NB0 / 16, NCH2 = NB2 / 16;  // 8, 4
static constexpr int CS0_OFF = 0;                       // [8][1000]
static constexpr int CS2_OFF = NCH0 * 1000;             // 8000, [4][5000]
static constexpr int CS3_OFF = CS2_OFF + NCH2 * 5000;   // 28000, [4][5000] -> total 48000
static constexpr int NHIST = NB0 + NB2 + NB3;           // 256
static constexpr int NBLK_R1 = (300000 + 255) / 256;    // 1172

__device__ __forceinline__ float b2f(ush b) { return __uint_as_float(((unsigned)b) << 16); }
__device__ __forceinline__ ush f2b(float f) {
    unsigned u = __float_as_uint(f);
    return (ush)((u + 0x7FFFu + ((u >> 16) & 1u)) >> 16);
}

// ---------------------------------------------------------------------------
// Input dtype detection (fp32 vs bf16) — scan for bf16 NaN/Inf bit patterns.
// ---------------------------------------------------------------------------
__global__ __launch_bounds__(256) void detect_kernel(const ush* __restrict__ xp,
                                                     int* __restrict__ flag) {
    __shared__ int s;
    if (threadIdx.x == 0) s = 0;
    __syncthreads();
    int c = 0;
    for (int i = threadIdx.x; i < 16384; i += 256) {
        ush h = xp[i];
        if ((h & 0x7F80) == 0x7F80) c = 1;
    }
    if (c) atomicOr(&s, 1);
    __syncthreads();
    if (threadIdx.x == 0) *flag = s;
}

struct ConvArgs {
    const void* src[21];
    long cum[22];
};

__global__ __launch_bounds__(256) void convert_kernel(ConvArgs a, ush* __restrict__ dst,
                                                      long total, const int* __restrict__ flag) {
    const int f = *flag;
    for (long g = (long)blockIdx.x * 256 + threadIdx.x; g < total; g += (long)gridDim.x * 256) {
        int t = 0;
        while (g >= a.cum[t + 1]) t++;
        long i = g - a.cum[t];
        float v = f ? ((const float*)a.src[t])[i] : b2f(((const ush*)a.src[t])[i]);
        dst[g] = f2b(v);
    }
}

// canonical-block element offsets (bf16 elements)
static constexpr size_t OFF_XP = 0;
static constexpr size_t OFF_XD = 6400000;
static constexpr size_t OFF_XS = 6528000;
static constexpr size_t OFF_WINP = 6848000;
static constexpr size_t OFF_BINP = 6852096;
static constexpr size_t OFF_WIND = 6852160;
static constexpr size_t OFF_BIND = 6860352;
static constexpr size_t OFF_WINS = 6860416;
static constexpr size_t OFF_BINS = 6864512;
static constexpr size_t OFF_WK = 6864576;
static constexpr size_t OFF_BK = 6889152;
static constexpr size_t OFF_WQ = 6889536;
static constexpr size_t OFF_BQ = 6914112;
static constexpr size_t OFF_WV = 6914496;
static constexpr size_t OFF_BV = 6939072;
static constexpr size_t OFF_WA = 6939456;
static constexpr size_t OFF_BA = 6964032;
static constexpr size_t OFF_AREL = 6964416;
static constexpr size_t OFF_MREL = 6972608;
static constexpr size_t OFF_PREL = 6980800;
static constexpr size_t OFF_SKIP = 6980832;
static constexpr size_t CW_TOTAL = 6980838;

// ---------------------------------------------------------------------------
// Hist-CSR. r0/r2/r3: per-block LDS histograms -> HB[block][dst] (no global
// atomics), 3-stage chunked scan over the block axis, LDS-cursor fill.
// r1 (patients, deg~3): per-edge global atomics (low contention), fused into
// the same dispatches via block ranges.
// ---------------------------------------------------------------------------
struct CsrB {
    const int* ei[3];  // r0, r2, r3 edge arrays
    const int* ei1;    // r1
};

__device__ __forceinline__ void hist_geom(int b, const CsrB& c, int& r, const int*& ei, int& E,
                                          int& ndst, int& e0, int& e1, int& hb) {
    if (b < NB0) {
        r = 0; ei = c.ei[0]; E = 300000; ndst = 1000;
        e0 = b * CH0; hb = HB0_OFF + b * 1000;
    } else if (b < NB0 + NB2) {
        r = 1; ei = c.ei[1]; E = 100000; ndst = 5000;
        e0 = (b - NB0) * CH2; hb = HB2_OFF + (b - NB0) * 5000;
    } else {
        r = 2; ei = c.ei[2]; E = 100000; ndst = 5000;
        e0 = (b - NB0 - NB2) * CH2; hb = HB3_OFF + (b - NB0 - NB2) * 5000;
    }
    e1 = min(E, e0 + ((r == 0) ? CH0 : CH2));
}

// blocks [0,256): hist count r0/r2/r3; blocks [256,1428): per-edge r1 count
__global__ __launch_bounds__(256) void count_kernel(CsrB c, int* __restrict__ HB,
                                                    int* __restrict__ cnt) {
    const int b = blockIdx.x;
    if (b >= NHIST) {
        int g = (b - NHIST) * 256 + threadIdx.x;
        if (g < 300000) atomicAdd(&cnt[1000 + c.ei1[300000 + g]], 1);
        return;
    }
    __shared__ int h[5000];
    int r, E, ndst, e0, e1, hb;
    const int* ei;
    hist_geom(b, c, r, ei, E, ndst, e0, e1, hb);
    for (int d = threadIdx.x; d < ndst; d += 256) h[d] = 0;
    __syncthreads();
    for (int e = e0 + threadIdx.x; e < e1; e += 256) atomicAdd(&h[ei[E + e]], 1);
    __syncthreads();
    for (int d = threadIdx.x; d < ndst; d += 256) HB[hb + d] = h[d];
}

__device__ __forceinline__ bool cs_geom(int g, int& idx0, int& step) {
    if (g >= 48000) return false;
    if (g < 8000) {
        int c = g / 1000, d = g % 1000;
        idx0 = HB0_OFF + c * 16 * 1000 + d; step = 1000;
    } else if (g < 28000) {
        int gg = g - 8000, c = gg / 5000, d = gg % 5000;
        idx0 = HB2_OFF + c * 16 * 5000 + d; step = 5000;
    } else {
        int gg = g - 28000, c = gg / 5000, d = gg % 5000;
        idx0 = HB3_OFF + c * 16 * 5000 + d; step = 5000;
    }
    return true;
}

__global__ __launch_bounds__(256) void sumHB_kernel(const int* __restrict__ HB,
                                                    int* __restrict__ CS) {
    int g = blockIdx.x * 256 + threadIdx.x;
    int idx0, step;
    if (!cs_geom(g, idx0, step)) return;
    int s = 0;
#pragma unroll
    for (int b = 0; b < 16; b++) s += HB[idx0 + b * step];
    CS[g] = s;
}

__global__ __launch_bounds__(256) void scanCS_kernel(int* __restrict__ CS,
                                                     int* __restrict__ cnt) {
    int d = blockIdx.x * 256 + threadIdx.x;
    if (d >= 11000) return;
    int ld, nch, cs0, step, roff;
    if (d < 1000) { ld = d; nch = NCH0; cs0 = CS0_OFF + ld; step = 1000; roff = 0; }
    else if (d < 6000) { ld = d - 1000; nch = NCH2; cs0 = CS2_OFF + ld; step = 5000; roff = 101000; }
    else { ld = d - 6000; nch = NCH2; cs0 = CS3_OFF + ld; step = 5000; roff = 106000; }
    int run = 0;
    for (int c = 0; c < nch; c++) {
        int t = CS[cs0 + c * step];
        CS[cs0 + c * step] = run;
        run += t;
    }
    cnt[roff + ld] = run;
}

__global__ __launch_bounds__(256) void fixHB_kernel(int* __restrict__ HB,
                                                    const int* __restrict__ CS) {
    int g = blockIdx.x * 256 + threadIdx.x;
    int idx0, step;
    if (!cs_geom(g, idx0, step)) return;
    int run = CS[g];
#pragma unroll
    for (int b = 0; b < 16; b++) {
        int t = HB[idx0 + b * step];
        HB[idx0 + b * step] = run;
        run += t;
    }
}

__global__ __launch_bounds__(256) void scanA_kernel(const int* __restrict__ cnt,
                                                    int* __restrict__ tmp,
                                                    int* __restrict__ part) {
    __shared__ int ls[256];
    const int t = threadIdx.x;
    const int base = blockIdx.x * 1024 + t * 4;
    int v[4];
#pragma unroll
    for (int j = 0; j < 4; j++) v[j] = (base + j < NC) ? cnt[base + j] : 0;
    int tsum = v[0] + v[1] + v[2] + v[3];
    ls[t] = tsum;
    __syncthreads();
    for (int off = 1; off < 256; off <<= 1) {
        int y = (t >= off) ? ls[t - off] : 0;
        __syncthreads();
        ls[t] += y;
        __syncthreads();
    }
    int run = ls[t] - tsum;
#pragma unroll
    for (int j = 0; j < 4; j++) {
        if (base + j < NC) tmp[base + j] = run;
        run += v[j];
    }
    if (t == 255) part[blockIdx.x] = ls[255];
}

__global__ __launch_bounds__(256) void scanB_kernel(int* __restrict__ part, int nb) {
    __shared__ int ls[256];
    const int t = threadIdx.x;
    int x = (t < nb) ? part[t] : 0;
    ls[t] = x;
    __syncthreads();
    for (int off = 1; off < 256; off <<= 1) {
        int y = (t >= off) ? ls[t - off] : 0;
        __syncthreads();
        ls[t] += y;
        __syncthreads();
    }
    if (t < nb) part[t] = ls[t] - x;
    if (t == nb - 1) part[nb] = ls[t];
}

__global__ __launch_bounds__(256) void scanC_kernel(const int* __restrict__ tmp,
                                                    const int* __restrict__ part,
                                                    int* __restrict__ rowptr) {
    int i = blockIdx.x * 256 + threadIdx.x;
    if (i > NC) return;
    rowptr[i] = (i == NC) ? part[(NC + 1023) / 1024] : tmp[i] + part[i >> 10];
}

// blocks [0,256): hist fill; blocks [256,1428): per-edge r1 fill
__global__ __launch_bounds__(256) void fill_kernel(CsrB c, const int* __restrict__ HB,
                                                   const int* __restrict__ rowptr,
                                                   int* __restrict__ fillpos,
                                                   int* __restrict__ col) {
    const int b = blockIdx.x;
    if (b >= NHIST) {
        int g = (b - NHIST) * 256 + threadIdx.x;
        if (g < 300000) {
            int gi = 1000 + c.ei1[300000 + g];
            int slot = rowptr[gi] + atomicAdd(&fillpos[gi], 1);
            col[slot] = c.ei1[g];
        }
        return;
    }
    __shared__ int h[5000];
    int r, E, ndst, e0, e1, hb;
    const int* ei;
    hist_geom(b, c, r, ei, E, ndst, e0, e1, hb);
    const int roff = (r == 0) ? 0 : (r == 1) ? 101000 : 106000;
    for (int d = threadIdx.x; d < ndst; d += 256) h[d] = rowptr[roff + d] + HB[hb + d];
    __syncthreads();
    for (int e = e0 + threadIdx.x; e < e1; e += 256) {
        int d = ei[E + e];
        int slot = atomicAdd(&h[d], 1);
        col[slot] = ei[e];
    }
}

// ---------------------------------------------------------------------------
// Fold a_rel/m_rel into effective K|V weights, bf16, fused per (l,r).
// ---------------------------------------------------------------------------
__global__ __launch_bounds__(256) void eff_kernel(const ush* __restrict__ CW,
                                                  ush* __restrict__ weff) {
    const int b = blockIdx.x;  // l*4+r
    const int l = b >> 2, r = b & 3;
    const int st_of[4] = {0, 1, 1, 0};
    const int st = st_of[r];
    ush* out = weff + (size_t)b * 8320;
    for (int idx = threadIdx.x; idx < 8320; idx += 256) {
        int n, k;
        if (idx < 8192) { k = idx >> 7; n = idx & 127; }
        else { k = -1; n = idx - 8192; }
        int kv = n >= 64;
        int j = n & 63, h = j >> 4, e = j & 15;
        const ush* W = CW + (kv ? OFF_WV : OFF_WK) + (size_t)(l * 3 + st) * 4096;
        const ush* B = CW + (kv ? OFF_BV : OFF_BK) + (size_t)(l * 3 + st) * 64;
        const ush* R = CW + (kv ? OFF_MREL : OFF_AREL) + (size_t)(l * 4 + r) * 1024;
        float acc = 0.f;
        if (k >= 0) {
#pragma unroll
            for (int d = 0; d < 16; d++)
                acc += b2f(W[k * 64 + h * 16 + d]) * b2f(R[h * 256 + d * 16 + e]);
        } else {
#pragma unroll
            for (int d = 0; d < 16; d++)
                acc += b2f(B[h * 16 + d]) * b2f(R[h * 256 + d * 16 + e]);
        }
        out[idx] = f2b(acc);
    }
}

// ---------------------------------------------------------------------------
// Shared MFMA tile body: Y[64 rows x NOUT] = X @ W + bias, rows at row0.
// ---------------------------------------------------------------------------
template <int K, int NOUT>
__device__ __forceinline__ void gemm_tile(const ush* __restrict__ X, const ush* __restrict__ W,
                                          const ush* __restrict__ Bb, ush* __restrict__ Y,
                                          int M, int row0) {
    constexpr int NF = (K / 32) * (NOUT / 16);
    __shared__ short sA[64][K + 8];
    __shared__ short sB[NF][512];
    const int tid = threadIdx.x;
    for (int cid = tid; cid < 64 * K / 8; cid += 256) {
        int r = cid / (K / 8), c0 = (cid % (K / 8)) * 8;
        int row = row0 + r;
        short8 v = {0, 0, 0, 0, 0, 0, 0, 0};
        if (row < M) v = *(const short8*)(const void*)(X + (size_t)row * K + c0);
        *(short8*)(&sA[r][c0]) = v;
    }
    for (int u = tid; u < NF * 64; u += 256) {
        int f = u >> 6, l = u & 63;
        int s = f / (NOUT / 16), c = f % (NOUT / 16);
        int kbase = 32 * s + ((l >> 4) << 3), n = 16 * c + (l & 15);
        short8 v;
#pragma unroll
        for (int j = 0; j < 8; j++) v[j] = (short)W[(size_t)(kbase + j) * NOUT + n];
        *(short8*)(&sB[f][l * 8]) = v;
    }
    __syncthreads();
    const int w = tid >> 6, l = tid & 63;
    floatx4 acc[NOUT / 16];
#pragma unroll
    for (int c = 0; c < NOUT / 16; c++) {
        float bv = b2f(Bb[16 * c + (l & 15)]);
        acc[c] = (floatx4){bv, bv, bv, bv};
    }
#pragma unroll
    for (int s = 0; s < K / 32; s++) {
        short8 a = *(const short8*)(&sA[16 * w + (l & 15)][32 * s + ((l >> 4) << 3)]);
#pragma unroll
        for (int c = 0; c < NOUT / 16; c++) {
            short8 b = *(const short8*)(&sB[s * (NOUT / 16) + c][l * 8]);
            acc[c] = __builtin_amdgcn_mfma_f32_16x16x32_bf16(a, b, acc[c], 0, 0, 0);
        }
    }
#pragma unroll
    for (int c = 0; c < NOUT / 16; c++)
#pragma unroll
        for (int r = 0; r < 4; r++) {
            int row = row0 + 16 * w + ((l >> 4) << 2) + r;
            if (row < M) Y[(size_t)row * NOUT + 16 * c + (l & 15)] = f2b(acc[c][r]);
        }
}

template <int K, int NOUT>
__global__ __launch_bounds__(256) void mfma_proj(const ush* __restrict__ X,
                                                 const ush* __restrict__ W,
                                                 const ush* __restrict__ bias,
                                                 ush* __restrict__ Y, int M) {
    gemm_tile<K, NOUT>(X, W, bias, Y, M, blockIdx.x * 64);
}

// Batched Q projection: blocks [0,1563) P | [1563,1579) D | [1579,1658) S
struct QArgs {
    const ush* X;
    ush* Q;
    const ush* W[3];
    const ush* Bb[3];
};
__global__ __launch_bounds__(256) void qproj_kernel(QArgs a) {
    const int b = blockIdx.x;
    int t, lb, M;
    size_t noff;
    if (b < 1563) { t = 0; lb = b; M = N_P; noff = 0; }
    else if (b < 1579) { t = 1; lb = b - 1563; M = N_D; noff = (size_t)N_P; }
    else { t = 2; lb = b - 1579; M = N_S; noff = (size_t)(N_P + N_D); }
    gemm_tile<64, 64>(a.X + noff * 64, a.W[t], a.Bb[t], a.Q + noff * 64, M, lb * 64);
}

// Batched KV projection: r0 P | r1 D | r2 D | r3 P -> per-relation KV tables
struct KVArgs {
    const ush* X[4];
    ush* Y[4];
    const ush* W[4];
    const ush* Bb[4];
};
__global__ __launch_bounds__(256) void kvproj_kernel(KVArgs a) {
    const int b = blockIdx.x;
    int r, lb, M;
    if (b < 1563) { r = 0; lb = b; M = N_P; }
    else if (b < 1579) { r = 1; lb = b - 1563; M = N_D; }
    else if (b < 1595) { r = 2; lb = b - 1579; M = N_D; }
    else { r = 3; lb = b - 1595; M = N_P; }
    gemm_tile<64, 128>(a.X[r], a.W[r], a.Bb[r], a.Y[r], M, lb * 64);
}

// ---------------------------------------------------------------------------
// Fused gather aggregation with degree-proportional lane parallelism.
// ---------------------------------------------------------------------------
struct AggrArgs {
    const int* rowptr;
    const int* col;
    const ush* KV[4];
    const ush* Q;
    const ush* prel;
    float* OUT;
};

template <int LANES>
__device__ __forceinline__ void seg_attn(const AggrArgs& a, int rel, int g, int h, int lane,
                                         const float* qf, float* o) {
    const int s0 = a.rowptr[g], s1 = a.rowptr[g + 1];
    const ush* KV = a.KV[rel];
    const float ps = b2f(a.prel[rel * 4 + h]) * 0.25f;
    float m = -1e30f, s = 0.f;
    float acc[16];
#pragma unroll
    for (int i = 0; i < 16; i++) acc[i] = 0.f;
    for (int j = s0 + lane; j < s1; j += LANES) {
        int src = a.col[j];
        const ush* kp = KV + (size_t)src * 128 + h * 16;
        short8 k0 = *(const short8*)(const void*)kp;
        short8 k1 = *(const short8*)(const void*)(kp + 8);
        short8 v0 = *(const short8*)(const void*)(kp + 64);
        short8 v1 = *(const short8*)(const void*)(kp + 72);
        float dot = 0.f;
#pragma unroll
        for (int i = 0; i < 8; i++) dot += qf[i] * b2f((ush)k0[i]);
#pragma unroll
        for (int i = 0; i < 8; i++) dot += qf[8 + i] * b2f((ush)k1[i]);
        float aa = dot * ps;
        float nm = fmaxf(m, aa);
        float e0 = __expf(m - nm), e1 = __expf(aa - nm);
        s = s * e0 + e1;
#pragma unroll
        for (int i = 0; i < 8; i++) acc[i] = acc[i] * e0 + e1 * b2f((ush)v0[i]);
#pragma unroll
        for (int i = 0; i < 8; i++) acc[8 + i] = acc[8 + i] * e0 + e1 * b2f((ush)v1[i]);
        m = nm;
    }
#pragma unroll
    for (int wd = LANES >> 1; wd >= 1; wd >>= 1) {
        float mo = __shfl_xor(m, wd);
        float so = __shfl_xor(s, wd);
        float nm = fmaxf(m, mo);
        float e0 = __expf(m - nm), e1 = __expf(mo - nm);
        s = s * e0 + so * e1;
#pragma unroll
        for (int i = 0; i < 16; i++) {
            float ao = __shfl_xor(acc[i], wd);
            acc[i] = acc[i] * e0 + ao * e1;
        }
        m = nm;
    }
    float inv = 1.f / (s + 1e-16f);
#pragma unroll
    for (int i = 0; i < 16; i++) o[i] += acc[i] * inv;
}

template <int LANES>
__device__ __forceinline__ void job_run(const AggrArgs& a, int wid, int nd, int rel, int roff,
                                        size_t xoff, int rel2, int roff2) {
    const int lane = wid % LANES;
    const int grp = wid / LANES;
    const int d = grp >> 2, h = grp & 3;
    if (d >= nd) return;
    const ush* qp = a.Q + xoff + (size_t)d * 64 + h * 16;
    short8 q0 = *(const short8*)(const void*)qp;
    short8 q1 = *(const short8*)(const void*)(qp + 8);
    float qf[16];
#pragma unroll
    for (int i = 0; i < 8; i++) { qf[i] = b2f((ush)q0[i]); qf[8 + i] = b2f((ush)q1[i]); }
    float o[16];
#pragma unroll
    for (int i = 0; i < 16; i++) o[i] = 0.f;
    seg_attn<LANES>(a, rel, roff + d, h, lane, qf, o);
    if (rel2 >= 0) seg_attn<LANES>(a, rel2, roff2 + d, h, lane, qf, o);
    if (lane == 0) {
        float* op = a.OUT + xoff + (size_t)d * 64 + h * 16;
#pragma unroll
        for (int i = 0; i < 4; i++)
            *(floatx4*)(op + 4 * i) =
                (floatx4){o[4 * i], o[4 * i + 1], o[4 * i + 2], o[4 * i + 3]};
    }
}

// blocks: [0,250) drugs L=16 | [250,563) diseases L=4 | [563,3688) patients L=2
__global__ __launch_bounds__(256) void aggr_kernel(AggrArgs a) {
    const int b = blockIdx.x, t = threadIdx.x;
    if (b < 250) {
        job_run<16>(a, b * 256 + t, N_D, 0, 0, (size_t)N_P * 64, -1, 0);
    } else if (b < 563) {
        job_run<4>(a, (b - 250) * 256 + t, N_S, 2, 101000, (size_t)(N_P + N_D) * 64, 3, 106000);
    } else {
        job_run<2>(a, (b - 563) * 256 + t, N_P, 1, 1000, 0, -1, 0);
    }
}

// ---------------------------------------------------------------------------
// Batched MFMA epilogue: x = s*(gelu(OUT) @ Wa + ba) + (1-s)*x.
// last==1: write final output (dtype per flag) to fout instead of X.
// ---------------------------------------------------------------------------
struct EpiArgs {
    const float* O;
    ush* X;
    const ush* W[3];
    const ush* Bb[3];
    const ush* skipv;  // 3 bf16 gates for this layer
    void* fout;
    const int* flag;
    int last;
};

__global__ __launch_bounds__(256) void epi_kernel(EpiArgs a) {
    const int b = blockIdx.x;
    int t, lb, M;
    size_t noff;
    if (b < 1563) { t = 0; lb = b; M = N_P; noff = 0; }
    else if (b < 1579) { t = 1; lb = b - 1563; M = N_D; noff = (size_t)N_P; }
    else { t = 2; lb = b - 1579; M = N_S; noff = (size_t)(N_P + N_D); }
    const float* O = a.O + noff * 64;
    ush* X = a.X + noff * 64;
    const ush* W = a.W[t];
    __shared__ short sA[64][72];
    __shared__ short sB[8][512];
    const int tid = threadIdx.x;
    const int row0 = lb * 64;
    for (int cid = tid; cid < 512; cid += 256) {
        int r = cid >> 3, c0 = (cid & 7) * 8;
        int row = row0 + r;
        short8 sv = {0, 0, 0, 0, 0, 0, 0, 0};
        if (row < M) {
#pragma unroll
            for (int j = 0; j < 8; j++) {
                float v = O[(size_t)row * 64 + c0 + j];
                sv[j] = (short)f2b(0.5f * v * (1.0f + erff(v * 0.70710678118654752f)));
            }
        }
        *(short8*)(&sA[r][c0]) = sv;
    }
    for (int u = tid; u < 512; u += 256) {
        int f = u >> 6, l = u & 63;
        int s = f >> 2, c = f & 3;
        int kbase = 32 * s + ((l >> 4) << 3), n = 16 * c + (l & 15);
        short8 v;
#pragma unroll
        for (int j = 0; j < 8; j++) v[j] = (short)W[(size_t)(kbase + j) * 64 + n];
        *(short8*)(&sB[f][l * 8]) = v;
    }
    __syncthreads();
    const int w = tid >> 6, l = tid & 63;
    const float sg = 1.f / (1.f + expf(-b2f(a.skipv[t])));
    floatx4 acc[4];
#pragma unroll
    for (int c = 0; c < 4; c++) {
        float bv = b2f(a.Bb[t][16 * c + (l & 15)]);
        acc[c] = (floatx4){bv, bv, bv, bv};
    }
#pragma unroll
    for (int s = 0; s < 2; s++) {
        short8 av = *(const short8*)(&sA[16 * w + (l & 15)][32 * s + ((l >> 4) << 3)]);
#pragma unroll
        for (int c = 0; c < 4; c++) {
            short8 bv = *(const short8*)(&sB[s * 4 + c][l * 8]);
            acc[c] = __builtin_amdgcn_mfma_f32_16x16x32_bf16(av, bv, acc[c], 0, 0, 0);
        }
    }
    const int fl = a.last ? *a.flag : 0;
#pragma unroll
    for (int c = 0; c < 4; c++)
#pragma unroll
        for (int r = 0; r < 4; r++) {
            int row = row0 + 16 * w + ((l >> 4) << 2) + r;
            if (row >= M) continue;
            size_t off = (size_t)row * 64 + 16 * c + (l & 15);
            float val = sg * acc[c][r] + (1.f - sg) * b2f(X[off]);
            if (!a.last) {
                X[off] = f2b(val);
            } else {
                size_t goff = (noff + row) * 64 + 16 * c + (l & 15);
                if (fl)
                    ((float*)a.fout)[goff] = val;
                else
                    ((ush*)a.fout)[goff] = f2b(val);
            }
        }
}

// ---------------------------------------------------------------------------
extern "C" void kernel_launch(void* const* d_in, const int* in_sizes, int n_in,
                              void* d_out, int out_size, void* d_ws, size_t ws_size,
                              hipStream_t stream) {
    // ---- Workspace layout (~124.5 MiB) ----
    char* w = (char*)d_ws;
    int* FLAG = (int*)w;    w += 64;
    ush* CW = (ush*)w;      w += ((CW_TOTAL * 2 + 63) / 64) * 64;
    ush* WEFFB = (ush*)w;   w += ((size_t)8 * 8320 * 2 + 63) / 64 * 64;
    ush* X = (ush*)w;       w += (size_t)NT * 64 * 2;
    ush* Q = (ush*)w;       w += (size_t)NT * 64 * 2;
    ush* KV0 = (ush*)w;     w += (size_t)N_P * 128 * 2;
    ush* KV1 = (ush*)w;     w += (size_t)N_D * 128 * 2;
    ush* KV2 = (ush*)w;     w += (size_t)N_D * 128 * 2;
    ush* KV3 = (ush*)w;     w += (size_t)N_P * 128 * 2;
    float* OUT = (float*)w; w += (size_t)NT * 64 * 4;
    int* CNT = (int*)w;     w += (size_t)NC * 4;  // r1 region doubles as fillpos
    int* TMP = (int*)w;     w += (size_t)NC * 4;
    int* PART = (int*)w;    w += 512;
    int* ROWPTR = (int*)w;  w += (size_t)(NC + 1) * 4;
    int* COL = (int*)w;     w += (size_t)E_TOT * 4;
    int* HB = (int*)OUT;           // 768000 ints (3 MB), dead before aggr
    int* CS = (int*)OUT + 800000;  // 48000 ints, same overlay

    // dtype detect + canonicalize
    detect_kernel<<<1, 256, 0, stream>>>((const ush*)d_in[0], FLAG);
    static const long sz[21] = {6400000, 128000, 320000, 4096, 64, 8192, 64, 4096, 64,
                                24576, 384, 24576, 384, 24576, 384, 24576, 384,
                                8192, 8192, 32, 6};
    ConvArgs ca;
    long cum = 0;
    for (int t = 0; t < 21; t++) {
        ca.src[t] = d_in[t];
        ca.cum[t] = cum;
        cum += sz[t];
    }
    ca.cum[21] = cum;
    convert_kernel<<<4096, 256, 0, stream>>>(ca, CW, cum, FLAG);

    // CSR build
    CsrB cb;
    cb.ei[0] = (const int*)d_in[21];  // r0: dst drugs
    cb.ei[1] = (const int*)d_in[23];  // r2: dst diseases
    cb.ei[2] = (const int*)d_in[24];  // r3: dst diseases
    cb.ei1 = (const int*)d_in[22];    // r1: dst patients
    hipMemsetAsync(CNT + 1000, 0, (size_t)100000 * 4, stream);  // r1 count region
    count_kernel<<<NHIST + NBLK_R1, 256, 0, stream>>>(cb, HB, CNT);
    sumHB_kernel<<<(48000 + 255) / 256, 256, 0, stream>>>(HB, CS);
    scanCS_kernel<<<(11000 + 255) / 256, 256, 0, stream>>>(CS, CNT);
    scanA_kernel<<<(NC + 1023) / 1024, 256, 0, stream>>>(CNT, TMP, PART);
    scanB_kernel<<<1, 256, 0, stream>>>(PART, (NC + 1023) / 1024);
    scanC_kernel<<<(NC + 1 + 255) / 256, 256, 0, stream>>>(TMP, PART, ROWPTR);
    hipMemsetAsync(CNT + 1000, 0, (size_t)100000 * 4, stream);  // reuse as r1 fillpos
    fixHB_kernel<<<(48000 + 255) / 256, 256, 0, stream>>>(HB, CS);
    fill_kernel<<<NHIST + NBLK_R1, 256, 0, stream>>>(cb, HB, ROWPTR, CNT, COL);

    eff_kernel<<<8, 256, 0, stream>>>(CW, WEFFB);

    const size_t toff[3] = {0, (size_t)N_P, (size_t)(N_P + N_D)};

    // input projections -> X
    mfma_proj<64, 64><<<(N_P + 63) / 64, 256, 0, stream>>>(
        CW + OFF_XP, CW + OFF_WINP, CW + OFF_BINP, X, N_P);
    mfma_proj<128, 64><<<(N_D + 63) / 64, 256, 0, stream>>>(
        CW + OFF_XD, CW + OFF_WIND, CW + OFF_BIND, X + toff[1] * 64, N_D);
    mfma_proj<64, 64><<<(N_S + 63) / 64, 256, 0, stream>>>(
        CW + OFF_XS, CW + OFF_WINS, CW + OFF_BINS, X + toff[2] * 64, N_S);

    for (int l = 0; l < 2; l++) {
        QArgs qa;
        qa.X = X;
        qa.Q = Q;
        for (int t = 0; t < 3; t++) {
            qa.W[t] = CW + OFF_WQ + (size_t)(l * 3 + t) * 4096;
            qa.Bb[t] = CW + OFF_BQ + (l * 3 + t) * 64;
        }
        qproj_kernel<<<1658, 256, 0, stream>>>(qa);

        KVArgs ka;
        ush* KVr[4] = {KV0, KV1, KV2, KV3};
        const int rst[4] = {0, 1, 1, 0};
        for (int r = 0; r < 4; r++) {
            ka.X[r] = X + toff[rst[r]] * 64;
            ka.Y[r] = KVr[r];
            const ush* we = WEFFB + (size_t)(l * 4 + r) * 8320;
            ka.W[r] = we;
            ka.Bb[r] = we + 8192;
        }
        kvproj_kernel<<<3158, 256, 0, stream>>>(ka);

        AggrArgs aa;
        aa.rowptr = ROWPTR;
        aa.col = COL;
        for (int r = 0; r < 4; r++) aa.KV[r] = KVr[r];
        aa.Q = Q;
        aa.prel = CW + OFF_PREL + l * 16;
        aa.OUT = OUT;
        aggr_kernel<<<3688, 256, 0, stream>>>(aa);

        EpiArgs ea;
        ea.O = OUT;
        ea.X = X;
        for (int t = 0; t < 3; t++) {
            ea.W[t] = CW + OFF_WA + (size_t)(l * 3 + t) * 4096;
            ea.Bb[t] = CW + OFF_BA + (l * 3 + t) * 64;
        }
        ea.skipv = CW + OFF_SKIP + l * 3;
        ea.fout = d_out;
        ea.flag = FLAG;
        ea.last = (l == 1) ? 1 : 0;
        epi_kernel<<<1658, 256, 0, stream>>>(ea);
    }
}

// Round 10
// 396.646 us; speedup vs baseline: 1.2336x; 1.0759x over previous
//
#include <hip/hip_runtime.h>
#include <cmath>

typedef unsigned short ush;  // bf16 raw bits
typedef __attribute__((ext_vector_type(8))) short short8;
typedef __attribute__((ext_vector_type(4))) float floatx4;

static constexpr int N_P = 100000, N_D = 1000, N_S = 5000, NT = N_P + N_D + N_S;
static constexpr int NC = 111000;  // concatenated dst slots: r0:1000 | r1:100000 | r2:5000 | r3:5000
static constexpr int E_TOT = 800000;

// hist-CSR geometry
static constexpr int NB0 = 128, NB2 = 64, NB3 = 64;
static constexpr int CH0 = (300000 + NB0 - 1) / NB0;  // 2344
static constexpr int CH2 = (100000 + NB2 - 1) / NB2;  // 1563
static constexpr int HB0_OFF = 0;
static constexpr int HB2_OFF = NB0 * 1000;            // 128000
static constexpr int HB3_OFF = HB2_OFF + NB2 * 5000;  // 448000 -> total 768000
static constexpr int NCH0 = NB0 / 16, NCH2 = NB2 / 16;  // 8, 4
static constexpr int CS0_OFF = 0;
static constexpr int CS2_OFF = NCH0 * 1000;            // 8000
static constexpr int CS3_OFF = CS2_OFF + NCH2 * 5000;  // 28000 -> total 48000
static constexpr int NHIST = NB0 + NB2 + NB3;          // 256
static constexpr int NBLK_R1 = (300000 + 255) / 256;   // 1172
static constexpr int NZB = (100000 + 255) / 256;       // 391 zero-blocks for CNT r1

__device__ __forceinline__ float b2f(ush b) { return __uint_as_float(((unsigned)b) << 16); }
__device__ __forceinline__ ush f2b(float f) {
    unsigned u = __float_as_uint(f);
    return (ush)((u + 0x7FFFu + ((u >> 16) & 1u)) >> 16);
}

// ---------------------------------------------------------------------------
// Input dtype detection (fp32 vs bf16) — scan for bf16 NaN/Inf bit patterns.
// ---------------------------------------------------------------------------
__global__ __launch_bounds__(256) void detect_kernel(const ush* __restrict__ xp,
                                                     int* __restrict__ flag) {
    __shared__ int s;
    if (threadIdx.x == 0) s = 0;
    __syncthreads();
    int c = 0;
    for (int i = threadIdx.x; i < 16384; i += 256) {
        ush h = xp[i];
        if ((h & 0x7F80) == 0x7F80) c = 1;
    }
    if (c) atomicOr(&s, 1);
    __syncthreads();
    if (threadIdx.x == 0) *flag = s;
}

// canonical weight-block offsets (bf16 elements), d_in[3..20]
static constexpr size_t OFF_WINP = 0;
static constexpr size_t OFF_BINP = 4096;
static constexpr size_t OFF_WIND = 4160;
static constexpr size_t OFF_BIND = 12352;
static constexpr size_t OFF_WINS = 12416;
static constexpr size_t OFF_BINS = 16512;
static constexpr size_t OFF_WK = 16576;
static constexpr size_t OFF_BK = 41152;
static constexpr size_t OFF_WQ = 41536;
static constexpr size_t OFF_BQ = 66112;
static constexpr size_t OFF_WV = 66496;
static constexpr size_t OFF_BV = 91072;
static constexpr size_t OFF_WA = 91456;
static constexpr size_t OFF_BA = 116032;
static constexpr size_t OFF_AREL = 116416;
static constexpr size_t OFF_MREL = 124608;
static constexpr size_t OFF_PREL = 132800;
static constexpr size_t OFF_SKIP = 132832;
static constexpr size_t CW_TOTAL = 132838;
static constexpr int NCONVB = (int)((CW_TOTAL + 255) / 256);  // 519

struct ConvArgs {
    const void* src[18];
    long cum[19];
};

// blocks [0,NCONVB): convert weights; [NCONVB, NCONVB+NZB): zero CNT r1 region
__global__ __launch_bounds__(256) void convert_kernel(ConvArgs a, ush* __restrict__ dst,
                                                      int* __restrict__ cnt_r1,
                                                      const int* __restrict__ flag) {
    const int b = blockIdx.x;
    if (b >= NCONVB) {
        int g = (b - NCONVB) * 256 + threadIdx.x;
        if (g < 100000) cnt_r1[g] = 0;
        return;
    }
    const int f = *flag;
    long g = (long)b * 256 + threadIdx.x;
    if (g >= (long)CW_TOTAL) return;
    int t = 0;
    while (g >= a.cum[t + 1]) t++;
    long i = g - a.cum[t];
    float v = f ? ((const float*)a.src[t])[i] : b2f(((const ush*)a.src[t])[i]);
    dst[g] = f2b(v);
}

// ---------------------------------------------------------------------------
// Hist-CSR (r0/r2/r3 LDS histograms, chunked block-axis scan; r1 per-edge).
// ---------------------------------------------------------------------------
struct CsrB {
    const int* ei[3];  // r0, r2, r3 edge arrays
    const int* ei1;    // r1
};

__device__ __forceinline__ void hist_geom(int b, const CsrB& c, int& r, const int*& ei, int& E,
                                          int& ndst, int& e0, int& e1, int& hb) {
    if (b < NB0) {
        r = 0; ei = c.ei[0]; E = 300000; ndst = 1000;
        e0 = b * CH0; hb = HB0_OFF + b * 1000;
    } else if (b < NB0 + NB2) {
        r = 1; ei = c.ei[1]; E = 100000; ndst = 5000;
        e0 = (b - NB0) * CH2; hb = HB2_OFF + (b - NB0) * 5000;
    } else {
        r = 2; ei = c.ei[2]; E = 100000; ndst = 5000;
        e0 = (b - NB0 - NB2) * CH2; hb = HB3_OFF + (b - NB0 - NB2) * 5000;
    }
    e1 = min(E, e0 + ((r == 0) ? CH0 : CH2));
}

__global__ __launch_bounds__(256) void count_kernel(CsrB c, int* __restrict__ HB,
                                                    int* __restrict__ cnt) {
    const int b = blockIdx.x;
    if (b >= NHIST) {
        int g = (b - NHIST) * 256 + threadIdx.x;
        if (g < 300000) atomicAdd(&cnt[1000 + c.ei1[300000 + g]], 1);
        return;
    }
    __shared__ int h[5000];
    int r, E, ndst, e0, e1, hb;
    const int* ei;
    hist_geom(b, c, r, ei, E, ndst, e0, e1, hb);
    for (int d = threadIdx.x; d < ndst; d += 256) h[d] = 0;
    __syncthreads();
    for (int e = e0 + threadIdx.x; e < e1; e += 256) atomicAdd(&h[ei[E + e]], 1);
    __syncthreads();
    for (int d = threadIdx.x; d < ndst; d += 256) HB[hb + d] = h[d];
}

__device__ __forceinline__ bool cs_geom(int g, int& idx0, int& step) {
    if (g >= 48000) return false;
    if (g < 8000) {
        int c = g / 1000, d = g % 1000;
        idx0 = HB0_OFF + c * 16 * 1000 + d; step = 1000;
    } else if (g < 28000) {
        int gg = g - 8000, c = gg / 5000, d = gg % 5000;
        idx0 = HB2_OFF + c * 16 * 5000 + d; step = 5000;
    } else {
        int gg = g - 28000, c = gg / 5000, d = gg % 5000;
        idx0 = HB3_OFF + c * 16 * 5000 + d; step = 5000;
    }
    return true;
}

__global__ __launch_bounds__(256) void sumHB_kernel(const int* __restrict__ HB,
                                                    int* __restrict__ CS) {
    int g = blockIdx.x * 256 + threadIdx.x;
    int idx0, step;
    if (!cs_geom(g, idx0, step)) return;
    int s = 0;
#pragma unroll
    for (int b = 0; b < 16; b++) s += HB[idx0 + b * step];
    CS[g] = s;
}

__global__ __launch_bounds__(256) void scanCS_kernel(int* __restrict__ CS,
                                                     int* __restrict__ cnt) {
    int d = blockIdx.x * 256 + threadIdx.x;
    if (d >= 11000) return;
    int ld, nch, cs0, step, roff;
    if (d < 1000) { ld = d; nch = NCH0; cs0 = CS0_OFF + ld; step = 1000; roff = 0; }
    else if (d < 6000) { ld = d - 1000; nch = NCH2; cs0 = CS2_OFF + ld; step = 5000; roff = 101000; }
    else { ld = d - 6000; nch = NCH2; cs0 = CS3_OFF + ld; step = 5000; roff = 106000; }
    int run = 0;
    for (int c = 0; c < nch; c++) {
        int t = CS[cs0 + c * step];
        CS[cs0 + c * step] = run;
        run += t;
    }
    cnt[roff + ld] = run;
}

__global__ __launch_bounds__(256) void fixHB_kernel(int* __restrict__ HB,
                                                    const int* __restrict__ CS) {
    int g = blockIdx.x * 256 + threadIdx.x;
    int idx0, step;
    if (!cs_geom(g, idx0, step)) return;
    int run = CS[g];
#pragma unroll
    for (int b = 0; b < 16; b++) {
        int t = HB[idx0 + b * step];
        HB[idx0 + b * step] = run;
        run += t;
    }
}

__global__ __launch_bounds__(256) void scanA_kernel(const int* __restrict__ cnt,
                                                    int* __restrict__ tmp,
                                                    int* __restrict__ part) {
    __shared__ int ls[256];
    const int t = threadIdx.x;
    const int base = blockIdx.x * 1024 + t * 4;
    int v[4];
#pragma unroll
    for (int j = 0; j < 4; j++) v[j] = (base + j < NC) ? cnt[base + j] : 0;
    int tsum = v[0] + v[1] + v[2] + v[3];
    ls[t] = tsum;
    __syncthreads();
    for (int off = 1; off < 256; off <<= 1) {
        int y = (t >= off) ? ls[t - off] : 0;
        __syncthreads();
        ls[t] += y;
        __syncthreads();
    }
    int run = ls[t] - tsum;
#pragma unroll
    for (int j = 0; j < 4; j++) {
        if (base + j < NC) tmp[base + j] = run;
        run += v[j];
    }
    if (t == 255) part[blockIdx.x] = ls[255];
}

__global__ __launch_bounds__(256) void scanB_kernel(int* __restrict__ part, int nb) {
    __shared__ int ls[256];
    const int t = threadIdx.x;
    int x = (t < nb) ? part[t] : 0;
    ls[t] = x;
    __syncthreads();
    for (int off = 1; off < 256; off <<= 1) {
        int y = (t >= off) ? ls[t - off] : 0;
        __syncthreads();
        ls[t] += y;
        __syncthreads();
    }
    if (t < nb) part[t] = ls[t] - x;
    if (t == nb - 1) part[nb] = ls[t];
}

static constexpr int NSCB = (NC + 1 + 255) / 256;  // 434
// blocks [0,NSCB): rowptr; [NSCB, NSCB+NZB): zero CNT r1 region (fillpos reuse)
__global__ __launch_bounds__(256) void scanC_kernel(const int* __restrict__ tmp,
                                                    const int* __restrict__ part,
                                                    int* __restrict__ rowptr,
                                                    int* __restrict__ cnt_r1) {
    const int b = blockIdx.x;
    if (b >= NSCB) {
        int g = (b - NSCB) * 256 + threadIdx.x;
        if (g < 100000) cnt_r1[g] = 0;
        return;
    }
    int i = b * 256 + threadIdx.x;
    if (i > NC) return;
    rowptr[i] = (i == NC) ? part[(NC + 1023) / 1024] : tmp[i] + part[i >> 10];
}

__global__ __launch_bounds__(256) void fill_kernel(CsrB c, const int* __restrict__ HB,
                                                   const int* __restrict__ rowptr,
                                                   int* __restrict__ fillpos,
                                                   int* __restrict__ col) {
    const int b = blockIdx.x;
    if (b >= NHIST) {
        int g = (b - NHIST) * 256 + threadIdx.x;
        if (g < 300000) {
            int gi = 1000 + c.ei1[300000 + g];
            int slot = rowptr[gi] + atomicAdd(&fillpos[gi], 1);
            col[slot] = c.ei1[g];
        }
        return;
    }
    __shared__ int h[5000];
    int r, E, ndst, e0, e1, hb;
    const int* ei;
    hist_geom(b, c, r, ei, E, ndst, e0, e1, hb);
    const int roff = (r == 0) ? 0 : (r == 1) ? 101000 : 106000;
    for (int d = threadIdx.x; d < ndst; d += 256) h[d] = rowptr[roff + d] + HB[hb + d];
    __syncthreads();
    for (int e = e0 + threadIdx.x; e < e1; e += 256) {
        int d = ei[E + e];
        int slot = atomicAdd(&h[d], 1);
        col[slot] = ei[e];
    }
}

// ---------------------------------------------------------------------------
// Fold a_rel/m_rel into effective K|V weights, bf16, fused per (l,r).
// ---------------------------------------------------------------------------
__global__ __launch_bounds__(256) void eff_kernel(const ush* __restrict__ CW,
                                                  ush* __restrict__ weff) {
    const int b = blockIdx.x;  // l*4+r
    const int l = b >> 2, r = b & 3;
    const int st_of[4] = {0, 1, 1, 0};
    const int st = st_of[r];
    ush* out = weff + (size_t)b * 8320;
    for (int idx = threadIdx.x; idx < 8320; idx += 256) {
        int n, k;
        if (idx < 8192) { k = idx >> 7; n = idx & 127; }
        else { k = -1; n = idx - 8192; }
        int kv = n >= 64;
        int j = n & 63, h = j >> 4, e = j & 15;
        const ush* W = CW + (kv ? OFF_WV : OFF_WK) + (size_t)(l * 3 + st) * 4096;
        const ush* B = CW + (kv ? OFF_BV : OFF_BK) + (size_t)(l * 3 + st) * 64;
        const ush* R = CW + (kv ? OFF_MREL : OFF_AREL) + (size_t)(l * 4 + r) * 1024;
        float acc = 0.f;
        if (k >= 0) {
#pragma unroll
            for (int d = 0; d < 16; d++)
                acc += b2f(W[k * 64 + h * 16 + d]) * b2f(R[h * 256 + d * 16 + e]);
        } else {
#pragma unroll
            for (int d = 0; d < 16; d++)
                acc += b2f(B[h * 16 + d]) * b2f(R[h * 256 + d * 16 + e]);
        }
        out[idx] = f2b(acc);
    }
}

// ---------------------------------------------------------------------------
// MFMA building blocks with caller-provided LDS (max-not-sum carving).
// ---------------------------------------------------------------------------
template <int K>
__device__ __forceinline__ void stage_A(short* sA, const ush* __restrict__ X, int M, int row0) {
    for (int cid = threadIdx.x; cid < 64 * K / 8; cid += 256) {
        int r = cid / (K / 8), c0 = (cid % (K / 8)) * 8;
        int row = row0 + r;
        short8 v = {0, 0, 0, 0, 0, 0, 0, 0};
        if (row < M) v = *(const short8*)(const void*)(X + (size_t)row * K + c0);
        *(short8*)(&sA[r * (K + 8) + c0]) = v;
    }
}

template <int K>
__device__ __forceinline__ void stage_A_raw(short* sA, const void* __restrict__ X, int f,
                                            int M, int row0) {
    for (int cid = threadIdx.x; cid < 64 * K / 8; cid += 256) {
        int r = cid / (K / 8), c0 = (cid % (K / 8)) * 8;
        int row = row0 + r;
        short8 v = {0, 0, 0, 0, 0, 0, 0, 0};
        if (row < M) {
            if (f) {
                const floatx4* fp = (const floatx4*)((const float*)X + (size_t)row * K + c0);
                floatx4 f0 = fp[0], f1 = fp[1];
#pragma unroll
                for (int j = 0; j < 4; j++) v[j] = (short)f2b(f0[j]);
#pragma unroll
                for (int j = 0; j < 4; j++) v[4 + j] = (short)f2b(f1[j]);
            } else {
                v = *(const short8*)(const void*)((const ush*)X + (size_t)row * K + c0);
            }
        }
        *(short8*)(&sA[r * (K + 8) + c0]) = v;
    }
}

template <int K, int NOUT>
__device__ __forceinline__ void gemm_core(const short* sA, short* sB,
                                          const ush* __restrict__ W, const ush* __restrict__ Bb,
                                          ush* __restrict__ Y, int M, int row0) {
    constexpr int NF = (K / 32) * (NOUT / 16);
    const int tid = threadIdx.x;
    for (int u = tid; u < NF * 64; u += 256) {
        int f = u >> 6, l = u & 63;
        int s = f / (NOUT / 16), c = f % (NOUT / 16);
        int kbase = 32 * s + ((l >> 4) << 3), n = 16 * c + (l & 15);
        short8 v;
#pragma unroll
        for (int j = 0; j < 8; j++) v[j] = (short)W[(size_t)(kbase + j) * NOUT + n];
        *(short8*)(&sB[f * 512 + l * 8]) = v;
    }
    __syncthreads();
    const int w = tid >> 6, l = tid & 63;
    floatx4 acc[NOUT / 16];
#pragma unroll
    for (int c = 0; c < NOUT / 16; c++) {
        float bv = b2f(Bb[16 * c + (l & 15)]);
        acc[c] = (floatx4){bv, bv, bv, bv};
    }
#pragma unroll
    for (int s = 0; s < K / 32; s++) {
        short8 a = *(const short8*)(&sA[(16 * w + (l & 15)) * (K + 8) + 32 * s + ((l >> 4) << 3)]);
#pragma unroll
        for (int c = 0; c < NOUT / 16; c++) {
            short8 b = *(const short8*)(&sB[(s * (NOUT / 16) + c) * 512 + l * 8]);
            acc[c] = __builtin_amdgcn_mfma_f32_16x16x32_bf16(a, b, acc[c], 0, 0, 0);
        }
    }
#pragma unroll
    for (int c = 0; c < NOUT / 16; c++)
#pragma unroll
        for (int r = 0; r < 4; r++) {
            int row = row0 + 16 * w + ((l >> 4) << 2) + r;
            if (row < M) Y[(size_t)row * NOUT + 16 * c + (l & 15)] = f2b(acc[c][r]);
        }
}

// ---------------------------------------------------------------------------
// Fused input projections (reads raw inputs, dtype per flag): P | D | S.
// Dynamic LDS: K=128 worst case = 64*136 + 16*512 shorts = 33792 B.
// ---------------------------------------------------------------------------
struct InArgs {
    const void* raw[3];
    const ush* W[3];
    const ush* Bb[3];
    ush* X;
    const int* flag;
};

__global__ __launch_bounds__(256) void inproj_kernel(InArgs a) {
    extern __shared__ short smem[];
    const int b = blockIdx.x;
    const int f = *a.flag;
    if (b < 1563) {
        short* sA = smem;
        short* sB = smem + 64 * 72;
        stage_A_raw<64>(sA, a.raw[0], f, N_P, b * 64);
        gemm_core<64, 64>(sA, sB, a.W[0], a.Bb[0], a.X, N_P, b * 64);
    } else if (b < 1579) {
        short* sA = smem;
        short* sB = smem + 64 * 136;
        stage_A_raw<128>(sA, a.raw[1], f, N_D, (b - 1563) * 64);
        gemm_core<128, 64>(sA, sB, a.W[1], a.Bb[1], a.X + (size_t)N_P * 64, N_D,
                           (b - 1563) * 64);
    } else {
        short* sA = smem;
        short* sB = smem + 64 * 72;
        stage_A_raw<64>(sA, a.raw[2], f, N_S, (b - 1579) * 64);
        gemm_core<64, 64>(sA, sB, a.W[2], a.Bb[2], a.X + (size_t)(N_P + N_D) * 64, N_S,
                          (b - 1579) * 64);
    }
}

// ---------------------------------------------------------------------------
// Fused Q + KV projections, one dispatch. Dynamic LDS: max(Q,KV) = 25600 B.
// blocks [0,1658): Q (P|D|S); [1658,4816): KV (r0 P | r1 D | r2 D | r3 P).
// ---------------------------------------------------------------------------
struct QKVArgs {
    const ush* X;
    ush* Q;
    const ush* Wq[3];
    const ush* Bq[3];
    const ush* Xr[4];
    ush* Y[4];
    const ush* Wkv[4];
    const ush* Bkv[4];
};

__global__ __launch_bounds__(256) void qkv_kernel(QKVArgs a) {
    extern __shared__ short smem[];
    short* sA = smem;
    short* sB = smem + 64 * 72;
    const int b = blockIdx.x;
    if (b < 1658) {
        int t, lb, M;
        size_t noff;
        if (b < 1563) { t = 0; lb = b; M = N_P; noff = 0; }
        else if (b < 1579) { t = 1; lb = b - 1563; M = N_D; noff = (size_t)N_P; }
        else { t = 2; lb = b - 1579; M = N_S; noff = (size_t)(N_P + N_D); }
        stage_A<64>(sA, a.X + noff * 64, M, lb * 64);
        gemm_core<64, 64>(sA, sB, a.Wq[t], a.Bq[t], a.Q + noff * 64, M, lb * 64);
    } else {
        int bb = b - 1658;
        int r, lb, M;
        if (bb < 1563) { r = 0; lb = bb; M = N_P; }
        else if (bb < 1579) { r = 1; lb = bb - 1563; M = N_D; }
        else if (bb < 1595) { r = 2; lb = bb - 1579; M = N_D; }
        else { r = 3; lb = bb - 1595; M = N_P; }
        stage_A<64>(sA, a.Xr[r], M, lb * 64);
        gemm_core<64, 128>(sA, sB, a.Wkv[r], a.Bkv[r], a.Y[r], M, lb * 64);
    }
}

// ---------------------------------------------------------------------------
// Fused gather aggregation with degree-proportional lane parallelism.
// ---------------------------------------------------------------------------
struct AggrArgs {
    const int* rowptr;
    const int* col;
    const ush* KV[4];
    const ush* Q;
    const ush* prel;
    float* OUT;
};

template <int LANES>
__device__ __forceinline__ void seg_attn(const AggrArgs& a, int rel, int g, int h, int lane,
                                         const float* qf, float* o) {
    const int s0 = a.rowptr[g], s1 = a.rowptr[g + 1];
    const ush* KV = a.KV[rel];
    const float ps = b2f(a.prel[rel * 4 + h]) * 0.25f;
    float m = -1e30f, s = 0.f;
    float acc[16];
#pragma unroll
    for (int i = 0; i < 16; i++) acc[i] = 0.f;
    for (int j = s0 + lane; j < s1; j += LANES) {
        int src = a.col[j];
        const ush* kp = KV + (size_t)src * 128 + h * 16;
        short8 k0 = *(const short8*)(const void*)kp;
        short8 k1 = *(const short8*)(const void*)(kp + 8);
        short8 v0 = *(const short8*)(const void*)(kp + 64);
        short8 v1 = *(const short8*)(const void*)(kp + 72);
        float dot = 0.f;
#pragma unroll
        for (int i = 0; i < 8; i++) dot += qf[i] * b2f((ush)k0[i]);
#pragma unroll
        for (int i = 0; i < 8; i++) dot += qf[8 + i] * b2f((ush)k1[i]);
        float aa = dot * ps;
        float nm = fmaxf(m, aa);
        float e0 = __expf(m - nm), e1 = __expf(aa - nm);
        s = s * e0 + e1;
#pragma unroll
        for (int i = 0; i < 8; i++) acc[i] = acc[i] * e0 + e1 * b2f((ush)v0[i]);
#pragma unroll
        for (int i = 0; i < 8; i++) acc[8 + i] = acc[8 + i] * e0 + e1 * b2f((ush)v1[i]);
        m = nm;
    }
#pragma unroll
    for (int wd = LANES >> 1; wd >= 1; wd >>= 1) {
        float mo = __shfl_xor(m, wd);
        float so = __shfl_xor(s, wd);
        float nm = fmaxf(m, mo);
        float e0 = __expf(m - nm), e1 = __expf(mo - nm);
        s = s * e0 + so * e1;
#pragma unroll
        for (int i = 0; i < 16; i++) {
            float ao = __shfl_xor(acc[i], wd);
            acc[i] = acc[i] * e0 + ao * e1;
        }
        m = nm;
    }
    float inv = 1.f / (s + 1e-16f);
#pragma unroll
    for (int i = 0; i < 16; i++) o[i] += acc[i] * inv;
}

template <int LANES>
__device__ __forceinline__ void job_run(const AggrArgs& a, int wid, int nd, int rel, int roff,
                                        size_t xoff, int rel2, int roff2) {
    const int lane = wid % LANES;
    const int grp = wid / LANES;
    const int d = grp >> 2, h = grp & 3;
    if (d >= nd) return;
    const ush* qp = a.Q + xoff + (size_t)d * 64 + h * 16;
    short8 q0 = *(const short8*)(const void*)qp;
    short8 q1 = *(const short8*)(const void*)(qp + 8);
    float qf[16];
#pragma unroll
    for (int i = 0; i < 8; i++) { qf[i] = b2f((ush)q0[i]); qf[8 + i] = b2f((ush)q1[i]); }
    float o[16];
#pragma unroll
    for (int i = 0; i < 16; i++) o[i] = 0.f;
    seg_attn<LANES>(a, rel, roff + d, h, lane, qf, o);
    if (rel2 >= 0) seg_attn<LANES>(a, rel2, roff2 + d, h, lane, qf, o);
    if (lane == 0) {
        float* op = a.OUT + xoff + (size_t)d * 64 + h * 16;
#pragma unroll
        for (int i = 0; i < 4; i++)
            *(floatx4*)(op + 4 * i) =
                (floatx4){o[4 * i], o[4 * i + 1], o[4 * i + 2], o[4 * i + 3]};
    }
}

// blocks: [0,250) drugs L=16 | [250,563) diseases L=4 | [563,3688) patients L=2
__global__ __launch_bounds__(256) void aggr_kernel(AggrArgs a) {
    const int b = blockIdx.x, t = threadIdx.x;
    if (b < 250) {
        job_run<16>(a, b * 256 + t, N_D, 0, 0, (size_t)N_P * 64, -1, 0);
    } else if (b < 563) {
        job_run<4>(a, (b - 250) * 256 + t, N_S, 2, 101000, (size_t)(N_P + N_D) * 64, 3, 106000);
    } else {
        job_run<2>(a, (b - 563) * 256 + t, N_P, 1, 1000, 0, -1, 0);
    }
}

// ---------------------------------------------------------------------------
// Batched MFMA epilogue: x = s*(gelu(OUT) @ Wa + ba) + (1-s)*x.
// last==1: write final output (dtype per flag) to fout instead of X.
// ---------------------------------------------------------------------------
struct EpiArgs {
    const float* O;
    ush* X;
    const ush* W[3];
    const ush* Bb[3];
    const ush* skipv;
    void* fout;
    const int* flag;
    int last;
};

__global__ __launch_bounds__(256) void epi_kernel(EpiArgs a) {
    const int b = blockIdx.x;
    int t, lb, M;
    size_t noff;
    if (b < 1563) { t = 0; lb = b; M = N_P; noff = 0; }
    else if (b < 1579) { t = 1; lb = b - 1563; M = N_D; noff = (size_t)N_P; }
    else { t = 2; lb = b - 1579; M = N_S; noff = (size_t)(N_P + N_D); }
    const float* O = a.O + noff * 64;
    ush* X = a.X + noff * 64;
    const ush* W = a.W[t];
    __shared__ short sA[64 * 72];
    __shared__ short sB[8 * 512];
    const int tid = threadIdx.x;
    const int row0 = lb * 64;
    for (int cid = tid; cid < 512; cid += 256) {
        int r = cid >> 3, c0 = (cid & 7) * 8;
        int row = row0 + r;
        short8 sv = {0, 0, 0, 0, 0, 0, 0, 0};
        if (row < M) {
#pragma unroll
            for (int j = 0; j < 8; j++) {
                float v = O[(size_t)row * 64 + c0 + j];
                sv[j] = (short)f2b(0.5f * v * (1.0f + erff(v * 0.70710678118654752f)));
            }
        }
        *(short8*)(&sA[r * 72 + c0]) = sv;
    }
    __syncthreads();  // gemm_core has its own sync after B staging; keep A visible
    const float sg = 1.f / (1.f + expf(-b2f(a.skipv[t])));
    // inline B staging + MFMA (same as gemm_core but custom epilogue)
    for (int u = tid; u < 512; u += 256) {
        int f = u >> 6, l = u & 63;
        int s = f >> 2, c = f & 3;
        int kbase = 32 * s + ((l >> 4) << 3), n = 16 * c + (l & 15);
        short8 v;
#pragma unroll
        for (int j = 0; j < 8; j++) v[j] = (short)W[(size_t)(kbase + j) * 64 + n];
        *(short8*)(&sB[f * 512 + l * 8]) = v;
    }
    __syncthreads();
    const int w = tid >> 6, l = tid & 63;
    floatx4 acc[4];
#pragma unroll
    for (int c = 0; c < 4; c++) {
        float bv = b2f(a.Bb[t][16 * c + (l & 15)]);
        acc[c] = (floatx4){bv, bv, bv, bv};
    }
#pragma unroll
    for (int s = 0; s < 2; s++) {
        short8 av = *(const short8*)(&sA[(16 * w + (l & 15)) * 72 + 32 * s + ((l >> 4) << 3)]);
#pragma unroll
        for (int c = 0; c < 4; c++) {
            short8 bv = *(const short8*)(&sB[(s * 4 + c) * 512 + l * 8]);
            acc[c] = __builtin_amdgcn_mfma_f32_16x16x32_bf16(av, bv, acc[c], 0, 0, 0);
        }
    }
    const int fl = a.last ? *a.flag : 0;
#pragma unroll
    for (int c = 0; c < 4; c++)
#pragma unroll
        for (int r = 0; r < 4; r++) {
            int row = row0 + 16 * w + ((l >> 4) << 2) + r;
            if (row >= M) continue;
            size_t off = (size_t)row * 64 + 16 * c + (l & 15);
            float val = sg * acc[c][r] + (1.f - sg) * b2f(X[off]);
            if (!a.last) {
                X[off] = f2b(val);
            } else {
                size_t goff = (noff + row) * 64 + 16 * c + (l & 15);
                if (fl)
                    ((float*)a.fout)[goff] = val;
                else
                    ((ush*)a.fout)[goff] = f2b(val);
            }
        }
}

// ---------------------------------------------------------------------------
extern "C" void kernel_launch(void* const* d_in, const int* in_sizes, int n_in,
                              void* d_out, int out_size, void* d_ws, size_t ws_size,
                              hipStream_t stream) {
    // ---- Workspace layout ----
    char* w = (char*)d_ws;
    int* FLAG = (int*)w;    w += 64;
    ush* CW = (ush*)w;      w += ((CW_TOTAL * 2 + 63) / 64) * 64;
    ush* WEFFB = (ush*)w;   w += ((size_t)8 * 8320 * 2 + 63) / 64 * 64;
    ush* X = (ush*)w;       w += (size_t)NT * 64 * 2;
    ush* Q = (ush*)w;       w += (size_t)NT * 64 * 2;
    ush* KV0 = (ush*)w;     w += (size_t)N_P * 128 * 2;
    ush* KV1 = (ush*)w;     w += (size_t)N_D * 128 * 2;
    ush* KV2 = (ush*)w;     w += (size_t)N_D * 128 * 2;
    ush* KV3 = (ush*)w;     w += (size_t)N_P * 128 * 2;
    float* OUT = (float*)w; w += (size_t)NT * 64 * 4;
    int* CNT = (int*)w;     w += (size_t)NC * 4;  // r1 region doubles as fillpos
    int* TMP = (int*)w;     w += (size_t)NC * 4;
    int* PART = (int*)w;    w += 512;
    int* ROWPTR = (int*)w;  w += (size_t)(NC + 1) * 4;
    int* COL = (int*)w;     w += (size_t)E_TOT * 4;
    int* HB = (int*)OUT;           // 768000 ints, dead before aggr
    int* CS = (int*)OUT + 800000;  // 48000 ints, same overlay

    // dtype detect + weight canonicalize (+ zero CNT r1 region)
    detect_kernel<<<1, 256, 0, stream>>>((const ush*)d_in[0], FLAG);
    static const long sz[18] = {4096, 64, 8192, 64, 4096, 64, 24576, 384, 24576, 384,
                                24576, 384, 24576, 384, 8192, 8192, 32, 6};
    ConvArgs ca;
    long cum = 0;
    for (int t = 0; t < 18; t++) {
        ca.src[t] = d_in[3 + t];
        ca.cum[t] = cum;
        cum += sz[t];
    }
    ca.cum[18] = cum;
    convert_kernel<<<NCONVB + NZB, 256, 0, stream>>>(ca, CW, CNT + 1000, FLAG);

    // CSR build
    CsrB cb;
    cb.ei[0] = (const int*)d_in[21];
    cb.ei[1] = (const int*)d_in[23];
    cb.ei[2] = (const int*)d_in[24];
    cb.ei1 = (const int*)d_in[22];
    count_kernel<<<NHIST + NBLK_R1, 256, 0, stream>>>(cb, HB, CNT);
    sumHB_kernel<<<(48000 + 255) / 256, 256, 0, stream>>>(HB, CS);
    scanCS_kernel<<<(11000 + 255) / 256, 256, 0, stream>>>(CS, CNT);
    scanA_kernel<<<(NC + 1023) / 1024, 256, 0, stream>>>(CNT, TMP, PART);
    scanB_kernel<<<1, 256, 0, stream>>>(PART, (NC + 1023) / 1024);
    scanC_kernel<<<NSCB + NZB, 256, 0, stream>>>(TMP, PART, ROWPTR, CNT + 1000);
    fixHB_kernel<<<(48000 + 255) / 256, 256, 0, stream>>>(HB, CS);
    fill_kernel<<<NHIST + NBLK_R1, 256, 0, stream>>>(cb, HB, ROWPTR, CNT, COL);

    eff_kernel<<<8, 256, 0, stream>>>(CW, WEFFB);

    const size_t toff[3] = {0, (size_t)N_P, (size_t)(N_P + N_D)};

    // fused input projections (raw inputs)
    InArgs ia;
    ia.raw[0] = d_in[0];
    ia.raw[1] = d_in[1];
    ia.raw[2] = d_in[2];
    ia.W[0] = CW + OFF_WINP; ia.Bb[0] = CW + OFF_BINP;
    ia.W[1] = CW + OFF_WIND; ia.Bb[1] = CW + OFF_BIND;
    ia.W[2] = CW + OFF_WINS; ia.Bb[2] = CW + OFF_BINS;
    ia.X = X;
    ia.flag = FLAG;
    inproj_kernel<<<1658, 256, 33792, stream>>>(ia);

    for (int l = 0; l < 2; l++) {
        QKVArgs qk;
        qk.X = X;
        qk.Q = Q;
        ush* KVr[4] = {KV0, KV1, KV2, KV3};
        const int rst[4] = {0, 1, 1, 0};
        for (int t = 0; t < 3; t++) {
            qk.Wq[t] = CW + OFF_WQ + (size_t)(l * 3 + t) * 4096;
            qk.Bq[t] = CW + OFF_BQ + (l * 3 + t) * 64;
        }
        for (int r = 0; r < 4; r++) {
            qk.Xr[r] = X + toff[rst[r]] * 64;
            qk.Y[r] = KVr[r];
            const ush* we = WEFFB + (size_t)(l * 4 + r) * 8320;
            qk.Wkv[r] = we;
            qk.Bkv[r] = we + 8192;
        }
        qkv_kernel<<<4816, 256, 25600, stream>>>(qk);

        AggrArgs aa;
        aa.rowptr = ROWPTR;
        aa.col = COL;
        for (int r = 0; r < 4; r++) aa.KV[r] = KVr[r];
        aa.Q = Q;
        aa.prel = CW + OFF_PREL + l * 16;
        aa.OUT = OUT;
        aggr_kernel<<<3688, 256, 0, stream>>>(aa);

        EpiArgs ea;
        ea.O = OUT;
        ea.X = X;
        for (int t = 0; t < 3; t++) {
            ea.W[t] = CW + OFF_WA + (size_t)(l * 3 + t) * 4096;
            ea.Bb[t] = CW + OFF_BA + (l * 3 + t) * 64;
        }
        ea.skipv = CW + OFF_SKIP + l * 3;
        ea.fout = d_out;
        ea.flag = FLAG;
        ea.last = (l == 1) ? 1 : 0;
        epi_kernel<<<1658, 256, 0, stream>>>(ea);
    }
}